// Round 2
// baseline (31918.713 us; speedup 1.0000x reference)
//
#include <hip/hip_runtime.h>
#include <cstdint>

// Problem dims
#define TE    512
#define SD    128

typedef unsigned short u16;
typedef u16 u16x4 __attribute__((ext_vector_type(4)));
typedef u16 u16x8 __attribute__((ext_vector_type(8)));

// State region offsets (floats), relative to st pointer (st = d_ws + 67,108,864 B;
// earlier rounds proved ws_size >= 68.1 MB)
#define QO    0          // [32][1024]
#define SCO   32768      // [32][512]
#define BARO  49152      // grid-barrier counter (hole between SCO and CTXO)
#define CTXO  81920      // [32][1024]
#define YO    114688     // [32][128]
#define H0O   118784     // [2][32][512]
#define C0O   151552
#define H1O   184320
#define C1O   217088

__device__ __forceinline__ float b2f(u16 v) { return __uint_as_float(((unsigned)v) << 16); }
__device__ __forceinline__ u16 f2b(float f) {
  unsigned u = __float_as_uint(f);
  return (u16)((u + 0x7FFFu + ((u >> 16) & 1u)) >> 16);
}
__device__ __forceinline__ float tanh_f(float x) {
  float xc = fminf(12.f, fmaxf(-12.f, x));
  float e  = __expf(2.f * xc);
  return __fdividef(e - 1.f, e + 1.f);
}
__device__ __forceinline__ float sigm(float x) {
  float xc = fminf(30.f, fmaxf(-30.f, x));
  return __fdividef(1.f, 1.f + __expf(-xc));
}

// ---------------- NT GEMM: key=E@Wk^T, value=E@Wv^T (fp32 in, bf16 out) ----------------
__global__ __launch_bounds__(256)
void gemm_kv(const float* __restrict__ E, const float* __restrict__ Wk,
             const float* __restrict__ Wv, u16* __restrict__ key, u16* __restrict__ value) {
  const float* B = blockIdx.z ? Wv : Wk;
  u16* outp = blockIdx.z ? value : key;
  __shared__ float Asm[16][68], Bsm[16][68];
  const int tid = threadIdx.x;
  const int tm = blockIdx.x * 64, tn = blockIdx.y * 64;
  const int lr = tid >> 2, lc = (tid & 3) * 4;
  const int tx = tid & 15, ty = tid >> 4;
  float acc[4][4] = {};
  for (int k0 = 0; k0 < 1024; k0 += 16) {
    float4 av = *(const float4*)(&E[(long)(tm + lr) * 1024 + k0 + lc]);
    float4 bv = *(const float4*)(&B[(long)(tn + lr) * 1024 + k0 + lc]);
    Asm[lc][lr] = av.x; Asm[lc + 1][lr] = av.y; Asm[lc + 2][lr] = av.z; Asm[lc + 3][lr] = av.w;
    Bsm[lc][lr] = bv.x; Bsm[lc + 1][lr] = bv.y; Bsm[lc + 2][lr] = bv.z; Bsm[lc + 3][lr] = bv.w;
    __syncthreads();
#pragma unroll
    for (int kk = 0; kk < 16; ++kk) {
      float4 a4 = *(const float4*)(&Asm[kk][ty * 4]);
      float4 b4 = *(const float4*)(&Bsm[kk][tx * 4]);
      acc[0][0] += a4.x * b4.x; acc[0][1] += a4.x * b4.y; acc[0][2] += a4.x * b4.z; acc[0][3] += a4.x * b4.w;
      acc[1][0] += a4.y * b4.x; acc[1][1] += a4.y * b4.y; acc[1][2] += a4.y * b4.z; acc[1][3] += a4.y * b4.w;
      acc[2][0] += a4.z * b4.x; acc[2][1] += a4.z * b4.y; acc[2][2] += a4.z * b4.z; acc[2][3] += a4.z * b4.w;
      acc[3][0] += a4.w * b4.x; acc[3][1] += a4.w * b4.y; acc[3][2] += a4.w * b4.z; acc[3][3] += a4.w * b4.w;
    }
    __syncthreads();
  }
#pragma unroll
  for (int i = 0; i < 4; ++i)
#pragma unroll
    for (int j = 0; j < 4; ++j)
      outp[(long)(tm + ty * 4 + i) * 1024 + tn + tx * 4 + j] = f2b(acc[i][j]);
}

// ---------------- init: h/c -> parity-0 state, zero y, zero barrier ----------------
__global__ __launch_bounds__(256)
void init_state(const float* __restrict__ h0, const float* __restrict__ c0, float* __restrict__ st) {
  int i = blockIdx.x * 256 + threadIdx.x;   // 16384 threads
  st[H0O + i] = h0[i];
  st[H1O + i] = h0[16384 + i];
  st[C0O + i] = c0[i];
  st[C1O + i] = c0[16384 + i];
  if (i < 4096) st[YO + i] = 0.f;
  if (i == 0) *(unsigned*)(st + BARO) = 0u;
}

// ---------------- q0 = h0_layer0 @ Wq^T ----------------
__global__ __launch_bounds__(256)
void qproj(const float* __restrict__ h0, const float* __restrict__ Wq, float* __restrict__ st) {
  __shared__ float hr[512];
  const int b = blockIdx.x >> 2, o = (blockIdx.x & 3) * 256 + threadIdx.x;
  for (int i = threadIdx.x; i < 512; i += 256) hr[i] = h0[b * 512 + i];
  __syncthreads();
  float acc = 0.f;
  for (int k = 0; k < 512; k += 4) {
    float4 wv = *(const float4*)(&Wq[(long)o * 512 + k]);
    acc += hr[k] * wv.x + hr[k + 1] * wv.y + hr[k + 2] * wv.z + hr[k + 3] * wv.w;
  }
  st[QO + b * 1024 + o] = acc;
}

// ---------------- fused persistent decode loop (regular launch, manual grid barrier) ----------------
// 256 blocks x 256 threads, 1 block/CU nominal (capacity >= 2/CU so no deadlock).
// Phase A: scores (2 units/block) + fc(s-1) on blocks 0-31  -> bar
// Phase B: softmax + ctx (256 units)                        -> bar
// Phase C: LSTM0 (256)                                      -> bar
// Phase D: LSTM1 + q_next (256)                             -> bar
// Tail: fc for s = SD-1 (blocks 0-127)
__global__ __launch_bounds__(256, 2)
void decode_loop(const u16* __restrict__ key, const u16* __restrict__ value,
                 const float* __restrict__ We,
                 const float* __restrict__ wih0, const float* __restrict__ whh0,
                 const float* __restrict__ bih0, const float* __restrict__ bhh0,
                 const float* __restrict__ wih1, const float* __restrict__ whh1,
                 const float* __restrict__ bih1, const float* __restrict__ bhh1,
                 const float* __restrict__ Wq,
                 const float* __restrict__ fcw, const float* __restrict__ fcb,
                 float* st, float* out) {
  __shared__ float smem[7344];   // max over phases (phase D: 4224+1584+1536)
  const int tid = threadIdx.x, wv = tid >> 6, ln = tid & 63;
  const int bid = blockIdx.x;
  unsigned* bar = (unsigned*)(st + BARO);
  unsigned bt = 0;   // barrier count (uniform across threads/blocks)

  // grid barrier: release-fence, arrive, spin, acquire-fence
#define GBAR() do {                                                                   \
    ++bt;                                                                             \
    __syncthreads();                                                                  \
    if (tid == 0) {                                                                   \
      __threadfence();                                                                \
      __hip_atomic_fetch_add(bar, 1u, __ATOMIC_RELAXED, __HIP_MEMORY_SCOPE_AGENT);    \
      while (__hip_atomic_load(bar, __ATOMIC_RELAXED, __HIP_MEMORY_SCOPE_AGENT)       \
             < bt * 256u) { __builtin_amdgcn_s_sleep(1); }                            \
      __threadfence();                                                                \
    }                                                                                 \
    __syncthreads();                                                                  \
  } while (0)

  // step-invariant phase-A lane constants
  float wer[16];
#pragma unroll
  for (int j = 0; j < 16; j += 4) {
    float4 w4 = *(const float4*)(&We[ln * 16 + j]);
    wer[j] = w4.x; wer[j + 1] = w4.y; wer[j + 2] = w4.z; wer[j + 3] = w4.w;
  }

  for (int s = 0; s < SD; ++s) {
    const int p = s & 1;

    // =================== Phase A: raw scores (2 units) + fc(s-1) on blocks 0-31 ===================
    for (int u = bid; u < 512; u += 256) {
      const int ab = u >> 4, at0 = (u & 15) * 32;
      const u16* kbase = key + ((long)(ab * TE + at0) << 10) + ln * 16;
      float qr[16];
      const float* qp = st + QO + ab * 1024 + ln * 16;
#pragma unroll
      for (int j = 0; j < 16; j += 4) {
        float4 q4 = *(const float4*)(qp + j);
        qr[j] = q4.x; qr[j + 1] = q4.y; qr[j + 2] = q4.z; qr[j + 3] = q4.w;
      }
#pragma unroll
      for (int uu = 0; uu < 4; ++uu) {
        const int tt0 = wv + uu * 8, tt1 = wv + uu * 8 + 4;
        const u16* kr0 = kbase + ((long)tt0 << 10);
        const u16* kr1 = kbase + ((long)tt1 << 10);
        u16x8 a0 = *(const u16x8*)kr0, a1 = *(const u16x8*)(kr0 + 8);
        u16x8 b0 = *(const u16x8*)kr1, b1 = *(const u16x8*)(kr1 + 8);
        float p0 = 0.f, p1 = 0.f;
#pragma unroll
        for (int j = 0; j < 8; ++j) {
          p0 += tanh_f(qr[j] + b2f(a0[j])) * wer[j];
          p1 += tanh_f(qr[j] + b2f(b0[j])) * wer[j];
        }
#pragma unroll
        for (int j = 0; j < 8; ++j) {
          p0 += tanh_f(qr[8 + j] + b2f(a1[j])) * wer[8 + j];
          p1 += tanh_f(qr[8 + j] + b2f(b1[j])) * wer[8 + j];
        }
        for (int off = 32; off; off >>= 1) {
          p0 += __shfl_down(p0, off);
          p1 += __shfl_down(p1, off);
        }
        if (ln == 0) {
          st[SCO + ab * 512 + at0 + tt0] = p0;
          st[SCO + ab * 512 + at0 + tt1] = p1;
        }
      }
    }
    if (bid < 32 && s > 0) {
      // fc for previous step, batch b = bid (reads H1[p] from step s-1's D; writes YO read in C)
      float* h1s = smem;
      const int b = bid;
      for (int i = tid; i < 512; i += 256) h1s[i] = st[H1O + p * 16384 + b * 512 + i];
      __syncthreads();
#pragma unroll
      for (int oi = 0; oi < 32; ++oi) {
        const int o = wv * 32 + oi;
        float part = 0.f;
#pragma unroll
        for (int kk = 0; kk < 8; ++kk) {
          int k = kk * 64 + ln;
          part += h1s[k] * fcw[(long)o * 512 + k];
        }
        for (int off = 32; off; off >>= 1) part += __shfl_down(part, off);
        if (ln == 0) {
          float yh = fmaxf(part + fcb[o], 0.f);
          out[((long)b * SD + (s - 1)) * 128 + o] = yh;
          st[YO + b * 128 + o] = 1.f + yh;
        }
      }
    }
    GBAR();

    // =================== Phase B: softmax + ctx ===================
    {
      const int b = bid >> 3, dc = bid & 7;
      float* al = smem; float* rr = smem + 512; float* gp = smem + 520;
      al[tid]       = st[SCO + b * 512 + tid];
      al[tid + 256] = st[SCO + b * 512 + tid + 256];
      __syncthreads();
      float m = fmaxf(al[tid], al[tid + 256]);
      for (int off = 32; off; off >>= 1) m = fmaxf(m, __shfl_xor(m, off));
      if (ln == 0) rr[wv] = m;
      __syncthreads();
      const float M = fmaxf(fmaxf(rr[0], rr[1]), fmaxf(rr[2], rr[3]));
      float e0 = __expf(al[tid] - M), e1 = __expf(al[tid + 256] - M);
      float l = e0 + e1;
      for (int off = 32; off; off >>= 1) l += __shfl_xor(l, off);
      if (ln == 0) rr[4 + wv] = l;
      __syncthreads();
      const float inv = __fdividef(1.f, rr[4] + rr[5] + rr[6] + rr[7]);
      al[tid] = e0; al[tid + 256] = e1;
      __syncthreads();
      const int dl = (tid & 31) * 4, tg = tid >> 5;
      float a0 = 0.f, a1 = 0.f, a2 = 0.f, a3 = 0.f;
      const u16* vb = value + ((long)(b * TE) << 10) + dc * 128 + dl;
#pragma unroll 4
      for (int t = tg; t < 512; t += 8) {
        u16x4 vvv = *(const u16x4*)(vb + ((long)t << 10));
        float av = al[t];
        a0 += av * b2f(vvv[0]); a1 += av * b2f(vvv[1]);
        a2 += av * b2f(vvv[2]); a3 += av * b2f(vvv[3]);
      }
      float4 a4 = {a0, a1, a2, a3};
      *(float4*)(&gp[tg * 132 + dl]) = a4;
      __syncthreads();
      if (tid < 128) {
        float ssum = 0.f;
#pragma unroll
        for (int g = 0; g < 8; ++g) ssum += gp[g * 132 + tid];
        st[CTXO + b * 1024 + dc * 128 + tid] = ssum * inv;
      }
    }
    GBAR();

    // =================== Phase C: LSTM0 ===================
    {
      float* xs = smem;            // 32*132
      float* wr = smem + 4224;     // 8*132
      float* gp = smem + 5280;     // 4*32*8
      const int h0d = bid * 2;
      float acc[8];
#pragma unroll
      for (int r = 0; r < 8; ++r) acc[r] = 0.f;
      for (int ch = 0; ch < 13; ++ch) {
        const float* src; int stride, col0;
        if (ch == 0)      { src = st + YO;               stride = 128;  col0 = 0; }
        else if (ch <= 8) { src = st + CTXO;             stride = 1024; col0 = (ch - 1) * 128; }
        else              { src = st + H0O + p * 16384;  stride = 512;  col0 = (ch - 9) * 128; }
#pragma unroll
        for (int i = 0; i < 4; ++i) {
          int e4 = tid * 4 + i * 1024;
          int bs = e4 >> 7, j = e4 & 127;
          *(float4*)(&xs[bs * 132 + j]) = *(const float4*)(src + bs * stride + col0 + j);
        }
        {
          int e = tid * 4, r = e >> 7, j = e & 127;
          int g = r >> 1, hh = r & 1;
          const float* wsrc; long rb;
          if (ch <= 8) { wsrc = wih0; rb = (long)(g * 512 + h0d + hh) * 1152 + ch * 128; }
          else         { wsrc = whh0; rb = (long)(g * 512 + h0d + hh) * 512 + (ch - 9) * 128; }
          *(float4*)(&wr[r * 132 + j]) = *(const float4*)(&wsrc[rb + j]);
        }
        __syncthreads();
        const int b = tid & 31, j0 = (tid >> 5) * 16;
#pragma unroll
        for (int jj = 0; jj < 16; jj += 4) {
          const float4 xv = *(const float4*)(&xs[b * 132 + j0 + jj]);
#pragma unroll
          for (int r = 0; r < 8; ++r) {
            const float4 w4 = *(const float4*)(&wr[r * 132 + j0 + jj]);
            acc[r] += xv.x * w4.x + xv.y * w4.y + xv.z * w4.z + xv.w * w4.w;
          }
        }
        __syncthreads();
      }
#pragma unroll
      for (int r = 0; r < 8; ++r) acc[r] += __shfl_down(acc[r], 32);
      if (ln < 32) {
#pragma unroll
        for (int r = 0; r < 8; ++r) gp[(wv * 32 + ln) * 8 + r] = acc[r];
      }
      __syncthreads();
      if (tid < 64) {
        const int b = tid & 31, hh = tid >> 5, h = h0d + hh;
        float gg[4];
#pragma unroll
        for (int g = 0; g < 4; ++g) {
          int r = g * 2 + hh;
          gg[g] = gp[(0 * 32 + b) * 8 + r] + gp[(1 * 32 + b) * 8 + r] +
                  gp[(2 * 32 + b) * 8 + r] + gp[(3 * 32 + b) * 8 + r] +
                  bih0[g * 512 + h] + bhh0[g * 512 + h];
        }
        float ig = sigm(gg[0]), fg = sigm(gg[1]), gt = tanh_f(gg[2]), og = sigm(gg[3]);
        int si = b * 512 + h;
        float c  = st[C0O + p * 16384 + si];
        float cn = fg * c + ig * gt;
        float hn = og * tanh_f(cn);
        st[H0O + (p ^ 1) * 16384 + si] = hn;
        st[C0O + (p ^ 1) * 16384 + si] = cn;
      }
    }
    GBAR();

    // =================== Phase D: LSTM1 + q_next ===================
    {
      float* xs = smem;            // 32*132
      float* wr = smem + 4224;     // 12*132
      float* gp = smem + 5808;     // 4*32*12
      const int h0d = bid * 2;
      float acc[12];
#pragma unroll
      for (int r = 0; r < 12; ++r) acc[r] = 0.f;
      for (int ch = 0; ch < 8; ++ch) {
        const float* src = (ch < 4) ? (st + H0O + (p ^ 1) * 16384) : (st + H1O + p * 16384);
        const int col0 = (ch & 3) * 128;
#pragma unroll
        for (int i = 0; i < 4; ++i) {
          int e4 = tid * 4 + i * 1024;
          int bs = e4 >> 7, j = e4 & 127;
          *(float4*)(&xs[bs * 132 + j]) = *(const float4*)(src + bs * 512 + col0 + j);
        }
        {
          int e = tid * 4, r = e >> 7, j = e & 127;
          int g = r >> 1, hh = r & 1;
          const float* wsrc = (ch < 4) ? wih1 : whh1;
          long rb = (long)(g * 512 + h0d + hh) * 512 + col0;
          *(float4*)(&wr[r * 132 + j]) = *(const float4*)(&wsrc[rb + j]);
          if (ch < 4 && tid < 128) {
            int rq = e >> 7, j2 = e & 127;
            long rqb = (long)(4 * bid + rq) * 512 + col0;
            *(float4*)(&wr[(8 + rq) * 132 + j2]) = *(const float4*)(&Wq[rqb + j2]);
          }
        }
        __syncthreads();
        const int b = tid & 31, j0 = (tid >> 5) * 16;
#pragma unroll
        for (int jj = 0; jj < 16; jj += 4) {
          const float4 xv = *(const float4*)(&xs[b * 132 + j0 + jj]);
#pragma unroll
          for (int r = 0; r < 8; ++r) {
            const float4 w4 = *(const float4*)(&wr[r * 132 + j0 + jj]);
            acc[r] += xv.x * w4.x + xv.y * w4.y + xv.z * w4.z + xv.w * w4.w;
          }
          if (ch < 4) {
#pragma unroll
            for (int r = 8; r < 12; ++r) {
              const float4 w4 = *(const float4*)(&wr[r * 132 + j0 + jj]);
              acc[r] += xv.x * w4.x + xv.y * w4.y + xv.z * w4.z + xv.w * w4.w;
            }
          }
        }
        __syncthreads();
      }
#pragma unroll
      for (int r = 0; r < 12; ++r) acc[r] += __shfl_down(acc[r], 32);
      if (ln < 32) {
#pragma unroll
        for (int r = 0; r < 12; ++r) gp[(wv * 32 + ln) * 12 + r] = acc[r];
      }
      __syncthreads();
      if (tid < 64) {
        const int b = tid & 31, hh = tid >> 5, h = h0d + hh;
        float gg[4];
#pragma unroll
        for (int g = 0; g < 4; ++g) {
          int r = g * 2 + hh;
          gg[g] = gp[(0 * 32 + b) * 12 + r] + gp[(1 * 32 + b) * 12 + r] +
                  gp[(2 * 32 + b) * 12 + r] + gp[(3 * 32 + b) * 12 + r] +
                  bih1[g * 512 + h] + bhh1[g * 512 + h];
        }
        float ig = sigm(gg[0]), fg = sigm(gg[1]), gt = tanh_f(gg[2]), og = sigm(gg[3]);
        int si = b * 512 + h;
        float c  = st[C1O + p * 16384 + si];
        float cn = fg * c + ig * gt;
        float hn = og * tanh_f(cn);
        st[H1O + (p ^ 1) * 16384 + si] = hn;
        st[C1O + (p ^ 1) * 16384 + si] = cn;
        int r0 = 8 + 2 * hh;
        float q0 = gp[(0 * 32 + b) * 12 + r0]     + gp[(1 * 32 + b) * 12 + r0] +
                   gp[(2 * 32 + b) * 12 + r0]     + gp[(3 * 32 + b) * 12 + r0];
        float q1 = gp[(0 * 32 + b) * 12 + r0 + 1] + gp[(1 * 32 + b) * 12 + r0 + 1] +
                   gp[(2 * 32 + b) * 12 + r0 + 1] + gp[(3 * 32 + b) * 12 + r0 + 1];
        int o0 = 4 * bid + 2 * hh;
        st[QO + b * 1024 + o0]     = q0;
        st[QO + b * 1024 + o0 + 1] = q1;
      }
    }
    GBAR();
  }

  // =================== Tail: fc for step SD-1 (h1 at parity 0) ===================
  if (bid < 128) {
    float* h1s = smem;
    const int b = bid >> 2, og = (bid & 3) * 32;
    for (int i = tid; i < 512; i += 256) h1s[i] = st[H1O + b * 512 + i];
    __syncthreads();
#pragma unroll
    for (int oi = 0; oi < 8; ++oi) {
      const int o = og + wv * 8 + oi;
      float part = 0.f;
#pragma unroll
      for (int kk = 0; kk < 8; ++kk) {
        int k = kk * 64 + ln;
        part += h1s[k] * fcw[(long)o * 512 + k];
      }
      for (int off = 32; off; off >>= 1) part += __shfl_down(part, off);
      if (ln == 0) {
        float yh = fmaxf(part + fcb[o], 0.f);
        out[((long)b * SD + (SD - 1)) * 128 + o] = yh;
      }
    }
  }
#undef GBAR
}

extern "C" void kernel_launch(void* const* d_in, const int* in_sizes, int n_in,
                              void* d_out, int out_size, void* d_ws, size_t ws_size,
                              hipStream_t stream) {
  (void)in_sizes; (void)n_in; (void)out_size; (void)ws_size;
  float* out = (float*)d_out;

  const float* E    = (const float*)d_in[0];
  const float* h0   = (const float*)d_in[1];
  const float* c0   = (const float*)d_in[2];
  const float* Wk   = (const float*)d_in[3];
  const float* Wq   = (const float*)d_in[4];
  const float* Wv   = (const float*)d_in[5];
  const float* We   = (const float*)d_in[6];
  const float* wih0 = (const float*)d_in[7];
  const float* whh0 = (const float*)d_in[8];
  const float* bih0 = (const float*)d_in[9];
  const float* bhh0 = (const float*)d_in[10];
  const float* wih1 = (const float*)d_in[11];
  const float* whh1 = (const float*)d_in[12];
  const float* bih1 = (const float*)d_in[13];
  const float* bhh1 = (const float*)d_in[14];
  const float* fcw  = (const float*)d_in[15];
  const float* fcb  = (const float*)d_in[16];

  // ws layout: key bf16 33.5MB | value bf16 33.5MB | st ~1MB
  u16* key   = (u16*)d_ws;
  u16* value = key + 16777216;
  float* st  = (float*)d_ws + 16777216;   // byte 67,108,864

  gemm_kv<<<dim3(256, 16, 2), 256, 0, stream>>>(E, Wk, Wv, key, value);
  init_state<<<64, 256, 0, stream>>>(h0, c0, st);
  qproj<<<128, 256, 0, stream>>>(h0, Wq, st);

  decode_loop<<<256, 256, 0, stream>>>(key, value, We,
                                       wih0, whh0, bih0, bhh0,
                                       wih1, whh1, bih1, bhh1,
                                       Wq, fcw, fcb, st, out);
}

// Round 3
// 21636.409 us; speedup vs baseline: 1.4752x; 1.4752x over previous
//
#include <hip/hip_runtime.h>
#include <cstdint>

// Problem dims
#define TE    512
#define SD    128

typedef unsigned short u16;
typedef u16 u16x4 __attribute__((ext_vector_type(4)));
typedef u16 u16x8 __attribute__((ext_vector_type(8)));

// State region offsets (floats), relative to st pointer (st = d_ws + 67,108,864 B;
// earlier rounds proved ws_size >= 68.1 MB)
#define QO    0          // [32][1024]
#define SCO   32768      // [32][512]
#define BARO  49152      // grid-barrier arrival counter
#define FLGO  49216      // grid-barrier release flag (separate cache line)
#define CTXO  81920      // [32][1024]
#define YO    114688     // [32][128]
#define H0O   118784     // [2][32][512]
#define C0O   151552
#define H1O   184320
#define C1O   217088

__device__ __forceinline__ float b2f(u16 v) { return __uint_as_float(((unsigned)v) << 16); }
__device__ __forceinline__ u16 f2b(float f) {
  unsigned u = __float_as_uint(f);
  return (u16)((u + 0x7FFFu + ((u >> 16) & 1u)) >> 16);
}
__device__ __forceinline__ float tanh_f(float x) {
  float xc = fminf(12.f, fmaxf(-12.f, x));
  float e  = __expf(2.f * xc);
  return __fdividef(e - 1.f, e + 1.f);
}
__device__ __forceinline__ float sigm(float x) {
  float xc = fminf(30.f, fmaxf(-30.f, x));
  return __fdividef(1.f, 1.f + __expf(-xc));
}

// ---- device-coherent (sc1: bypass non-coherent per-XCD L2) state accessors ----
__device__ __forceinline__ void ld_dev4x4(const float* p0, const float* p1,
                                          const float* p2, const float* p3,
                                          float4& r0, float4& r1, float4& r2, float4& r3) {
  asm volatile(
    "global_load_dwordx4 %0, %4, off sc1\n\t"
    "global_load_dwordx4 %1, %5, off sc1\n\t"
    "global_load_dwordx4 %2, %6, off sc1\n\t"
    "global_load_dwordx4 %3, %7, off sc1\n\t"
    "s_waitcnt vmcnt(0)"
    : "=&v"(r0), "=&v"(r1), "=&v"(r2), "=&v"(r3)
    : "v"(p0), "v"(p1), "v"(p2), "v"(p3)
    : "memory");
}
__device__ __forceinline__ void ld_dev2(const float* p0, const float* p1, float& r0, float& r1) {
  asm volatile(
    "global_load_dword %0, %2, off sc1\n\t"
    "global_load_dword %1, %3, off sc1\n\t"
    "s_waitcnt vmcnt(0)"
    : "=&v"(r0), "=&v"(r1)
    : "v"(p0), "v"(p1)
    : "memory");
}
__device__ __forceinline__ float ld_dev1(const float* p) {
  float r;
  asm volatile("global_load_dword %0, %1, off sc1\n\ts_waitcnt vmcnt(0)"
               : "=&v"(r) : "v"(p) : "memory");
  return r;
}
__device__ __forceinline__ void st_dev1(float* p, float v) {
  asm volatile("global_store_dword %0, %1, off sc1" :: "v"(p), "v"(v) : "memory");
}

// ---------------- NT GEMM: key=E@Wk^T, value=E@Wv^T (fp32 in, bf16 out) ----------------
__global__ __launch_bounds__(256)
void gemm_kv(const float* __restrict__ E, const float* __restrict__ Wk,
             const float* __restrict__ Wv, u16* __restrict__ key, u16* __restrict__ value) {
  const float* B = blockIdx.z ? Wv : Wk;
  u16* outp = blockIdx.z ? value : key;
  __shared__ float Asm[16][68], Bsm[16][68];
  const int tid = threadIdx.x;
  const int tm = blockIdx.x * 64, tn = blockIdx.y * 64;
  const int lr = tid >> 2, lc = (tid & 3) * 4;
  const int tx = tid & 15, ty = tid >> 4;
  float acc[4][4] = {};
  for (int k0 = 0; k0 < 1024; k0 += 16) {
    float4 av = *(const float4*)(&E[(long)(tm + lr) * 1024 + k0 + lc]);
    float4 bv = *(const float4*)(&B[(long)(tn + lr) * 1024 + k0 + lc]);
    Asm[lc][lr] = av.x; Asm[lc + 1][lr] = av.y; Asm[lc + 2][lr] = av.z; Asm[lc + 3][lr] = av.w;
    Bsm[lc][lr] = bv.x; Bsm[lc + 1][lr] = bv.y; Bsm[lc + 2][lr] = bv.z; Bsm[lc + 3][lr] = bv.w;
    __syncthreads();
#pragma unroll
    for (int kk = 0; kk < 16; ++kk) {
      float4 a4 = *(const float4*)(&Asm[kk][ty * 4]);
      float4 b4 = *(const float4*)(&Bsm[kk][tx * 4]);
      acc[0][0] += a4.x * b4.x; acc[0][1] += a4.x * b4.y; acc[0][2] += a4.x * b4.z; acc[0][3] += a4.x * b4.w;
      acc[1][0] += a4.y * b4.x; acc[1][1] += a4.y * b4.y; acc[1][2] += a4.y * b4.z; acc[1][3] += a4.y * b4.w;
      acc[2][0] += a4.z * b4.x; acc[2][1] += a4.z * b4.y; acc[2][2] += a4.z * b4.z; acc[2][3] += a4.z * b4.w;
      acc[3][0] += a4.w * b4.x; acc[3][1] += a4.w * b4.y; acc[3][2] += a4.w * b4.z; acc[3][3] += a4.w * b4.w;
    }
    __syncthreads();
  }
#pragma unroll
  for (int i = 0; i < 4; ++i)
#pragma unroll
    for (int j = 0; j < 4; ++j)
      outp[(long)(tm + ty * 4 + i) * 1024 + tn + tx * 4 + j] = f2b(acc[i][j]);
}

// ---------------- init: h/c -> parity-0 state, zero y, zero barrier ----------------
__global__ __launch_bounds__(256)
void init_state(const float* __restrict__ h0, const float* __restrict__ c0, float* __restrict__ st) {
  int i = blockIdx.x * 256 + threadIdx.x;   // 16384 threads
  st[H0O + i] = h0[i];
  st[H1O + i] = h0[16384 + i];
  st[C0O + i] = c0[i];
  st[C1O + i] = c0[16384 + i];
  if (i < 4096) st[YO + i] = 0.f;
  if (i == 0) { *(unsigned*)(st + BARO) = 0u; *(unsigned*)(st + FLGO) = 0u; }
}

// ---------------- q0 = h0_layer0 @ Wq^T ----------------
__global__ __launch_bounds__(256)
void qproj(const float* __restrict__ h0, const float* __restrict__ Wq, float* __restrict__ st) {
  __shared__ float hr[512];
  const int b = blockIdx.x >> 2, o = (blockIdx.x & 3) * 256 + threadIdx.x;
  for (int i = threadIdx.x; i < 512; i += 256) hr[i] = h0[b * 512 + i];
  __syncthreads();
  float acc = 0.f;
  for (int k = 0; k < 512; k += 4) {
    float4 wv = *(const float4*)(&Wq[(long)o * 512 + k]);
    acc += hr[k] * wv.x + hr[k + 1] * wv.y + hr[k + 2] * wv.z + hr[k + 3] * wv.w;
  }
  st[QO + b * 1024 + o] = acc;
}

// ---------------- fused persistent decode loop (no L2 flush: sc1 state + flag barrier) ----------------
// 256 blocks x 256 threads. key/value/weights stay L2-cached; state via device-coherent sc1.
__global__ __launch_bounds__(256, 2)
void decode_loop(const u16* __restrict__ key, const u16* __restrict__ value,
                 const float* __restrict__ We,
                 const float* __restrict__ wih0, const float* __restrict__ whh0,
                 const float* __restrict__ bih0, const float* __restrict__ bhh0,
                 const float* __restrict__ wih1, const float* __restrict__ whh1,
                 const float* __restrict__ bih1, const float* __restrict__ bhh1,
                 const float* __restrict__ Wq,
                 const float* __restrict__ fcw, const float* __restrict__ fcb,
                 float* st, float* out) {
  __shared__ float smem[7344];   // max over phases (phase D: 4224+1584+1536)
  const int tid = threadIdx.x, wv = tid >> 6, ln = tid & 63;
  const int bid = blockIdx.x;
  unsigned* bar  = (unsigned*)(st + BARO);
  unsigned* flag = (unsigned*)(st + FLGO);
  unsigned bt = 0;

  // barrier: drain own stores, arrive once per block, last arriver releases via flag.
  // No threadfence: all cross-block data moves via sc1 (device-coherent) accesses.
#define GBAR() do {                                                                     \
    ++bt;                                                                               \
    asm volatile("s_waitcnt vmcnt(0)" ::: "memory");                                    \
    __syncthreads();                                                                    \
    if (tid == 0) {                                                                     \
      unsigned old = __hip_atomic_fetch_add(bar, 1u, __ATOMIC_RELAXED,                  \
                                            __HIP_MEMORY_SCOPE_AGENT);                  \
      if (old == bt * 256u - 1u) {                                                      \
        __hip_atomic_store(flag, bt, __ATOMIC_RELAXED, __HIP_MEMORY_SCOPE_AGENT);       \
      } else {                                                                          \
        while (__hip_atomic_load(flag, __ATOMIC_RELAXED, __HIP_MEMORY_SCOPE_AGENT)      \
               < bt) { __builtin_amdgcn_s_sleep(4); }                                   \
      }                                                                                 \
    }                                                                                   \
    __syncthreads();                                                                    \
  } while (0)

  // step-invariant phase-A lane constants
  float wer[16];
#pragma unroll
  for (int j = 0; j < 16; j += 4) {
    float4 w4 = *(const float4*)(&We[ln * 16 + j]);
    wer[j] = w4.x; wer[j + 1] = w4.y; wer[j + 2] = w4.z; wer[j + 3] = w4.w;
  }

  for (int s = 0; s < SD; ++s) {
    const int p = s & 1;

    // =================== Phase A: raw scores (2 units) + fc(s-1) on blocks 0-31 ===================
    for (int u = bid; u < 512; u += 256) {
      const int ab = u >> 4, at0 = (u & 15) * 32;
      const u16* kbase = key + ((long)(ab * TE + at0) << 10) + ln * 16;
      float qr[16];
      {
        const float* qp = st + QO + ab * 1024 + ln * 16;
        float4 q0, q1, q2, q3;
        ld_dev4x4(qp, qp + 4, qp + 8, qp + 12, q0, q1, q2, q3);
        qr[0] = q0.x; qr[1] = q0.y; qr[2]  = q0.z; qr[3]  = q0.w;
        qr[4] = q1.x; qr[5] = q1.y; qr[6]  = q1.z; qr[7]  = q1.w;
        qr[8] = q2.x; qr[9] = q2.y; qr[10] = q2.z; qr[11] = q2.w;
        qr[12] = q3.x; qr[13] = q3.y; qr[14] = q3.z; qr[15] = q3.w;
      }
#pragma unroll
      for (int uu = 0; uu < 4; ++uu) {
        const int tt0 = wv + uu * 8, tt1 = wv + uu * 8 + 4;
        const u16* kr0 = kbase + ((long)tt0 << 10);
        const u16* kr1 = kbase + ((long)tt1 << 10);
        u16x8 a0 = *(const u16x8*)kr0, a1 = *(const u16x8*)(kr0 + 8);
        u16x8 b0 = *(const u16x8*)kr1, b1 = *(const u16x8*)(kr1 + 8);
        float p0 = 0.f, p1 = 0.f;
#pragma unroll
        for (int j = 0; j < 8; ++j) {
          p0 += tanh_f(qr[j] + b2f(a0[j])) * wer[j];
          p1 += tanh_f(qr[j] + b2f(b0[j])) * wer[j];
        }
#pragma unroll
        for (int j = 0; j < 8; ++j) {
          p0 += tanh_f(qr[8 + j] + b2f(a1[j])) * wer[8 + j];
          p1 += tanh_f(qr[8 + j] + b2f(b1[j])) * wer[8 + j];
        }
        for (int off = 32; off; off >>= 1) {
          p0 += __shfl_down(p0, off);
          p1 += __shfl_down(p1, off);
        }
        if (ln == 0) {
          st_dev1(st + SCO + ab * 512 + at0 + tt0, p0);
          st_dev1(st + SCO + ab * 512 + at0 + tt1, p1);
        }
      }
    }
    if (bid < 32 && s > 0) {
      // fc for previous step, batch b = bid (reads H1[p] from step s-1's D; writes YO read in C)
      float* h1s = smem;
      const int b = bid;
      {
        const float* hp = st + H1O + p * 16384 + b * 512;
        float r0, r1;
        ld_dev2(hp + tid, hp + tid + 256, r0, r1);
        h1s[tid] = r0; h1s[tid + 256] = r1;
      }
      __syncthreads();
#pragma unroll
      for (int oi = 0; oi < 32; ++oi) {
        const int o = wv * 32 + oi;
        float part = 0.f;
#pragma unroll
        for (int kk = 0; kk < 8; ++kk) {
          int k = kk * 64 + ln;
          part += h1s[k] * fcw[(long)o * 512 + k];
        }
        for (int off = 32; off; off >>= 1) part += __shfl_down(part, off);
        if (ln == 0) {
          float yh = fmaxf(part + fcb[o], 0.f);
          out[((long)b * SD + (s - 1)) * 128 + o] = yh;
          st_dev1(st + YO + b * 128 + o, 1.f + yh);
        }
      }
    }
    GBAR();

    // =================== Phase B: softmax + ctx ===================
    {
      const int b = bid >> 3, dc = bid & 7;
      float* al = smem; float* rr = smem + 512; float* gp = smem + 520;
      {
        const float* sp = st + SCO + b * 512;
        float r0, r1;
        ld_dev2(sp + tid, sp + tid + 256, r0, r1);
        al[tid] = r0; al[tid + 256] = r1;
      }
      __syncthreads();
      float m = fmaxf(al[tid], al[tid + 256]);
      for (int off = 32; off; off >>= 1) m = fmaxf(m, __shfl_xor(m, off));
      if (ln == 0) rr[wv] = m;
      __syncthreads();
      const float M = fmaxf(fmaxf(rr[0], rr[1]), fmaxf(rr[2], rr[3]));
      float e0 = __expf(al[tid] - M), e1 = __expf(al[tid + 256] - M);
      float l = e0 + e1;
      for (int off = 32; off; off >>= 1) l += __shfl_xor(l, off);
      if (ln == 0) rr[4 + wv] = l;
      __syncthreads();
      const float inv = __fdividef(1.f, rr[4] + rr[5] + rr[6] + rr[7]);
      al[tid] = e0; al[tid + 256] = e1;
      __syncthreads();
      const int dl = (tid & 31) * 4, tg = tid >> 5;
      float a0 = 0.f, a1 = 0.f, a2 = 0.f, a3 = 0.f;
      const u16* vb = value + ((long)(b * TE) << 10) + dc * 128 + dl;
#pragma unroll 4
      for (int t = tg; t < 512; t += 8) {
        u16x4 vvv = *(const u16x4*)(vb + ((long)t << 10));
        float av = al[t];
        a0 += av * b2f(vvv[0]); a1 += av * b2f(vvv[1]);
        a2 += av * b2f(vvv[2]); a3 += av * b2f(vvv[3]);
      }
      float4 a4 = {a0, a1, a2, a3};
      *(float4*)(&gp[tg * 132 + dl]) = a4;
      __syncthreads();
      if (tid < 128) {
        float ssum = 0.f;
#pragma unroll
        for (int g = 0; g < 8; ++g) ssum += gp[g * 132 + tid];
        st_dev1(st + CTXO + b * 1024 + dc * 128 + tid, ssum * inv);
      }
    }
    GBAR();

    // =================== Phase C: LSTM0 ===================
    {
      float* xs = smem;            // 32*132
      float* wr = smem + 4224;     // 8*132
      float* gp = smem + 5280;     // 4*32*8
      const int h0d = bid * 2;
      float acc[8];
#pragma unroll
      for (int r = 0; r < 8; ++r) acc[r] = 0.f;
      for (int ch = 0; ch < 13; ++ch) {
        const float* src; int stride, col0;
        if (ch == 0)      { src = st + YO;               stride = 128;  col0 = 0; }
        else if (ch <= 8) { src = st + CTXO;             stride = 1024; col0 = (ch - 1) * 128; }
        else              { src = st + H0O + p * 16384;  stride = 512;  col0 = (ch - 9) * 128; }
        {
          int bs0 = (tid * 4) >> 7,          j0x = (tid * 4) & 127;
          int bs1 = (tid * 4 + 1024) >> 7,   j1x = (tid * 4 + 1024) & 127;
          int bs2 = (tid * 4 + 2048) >> 7,   j2x = (tid * 4 + 2048) & 127;
          int bs3 = (tid * 4 + 3072) >> 7,   j3x = (tid * 4 + 3072) & 127;
          float4 r0, r1, r2, r3;
          ld_dev4x4(src + bs0 * stride + col0 + j0x, src + bs1 * stride + col0 + j1x,
                    src + bs2 * stride + col0 + j2x, src + bs3 * stride + col0 + j3x,
                    r0, r1, r2, r3);
          *(float4*)(&xs[bs0 * 132 + j0x]) = r0;
          *(float4*)(&xs[bs1 * 132 + j1x]) = r1;
          *(float4*)(&xs[bs2 * 132 + j2x]) = r2;
          *(float4*)(&xs[bs3 * 132 + j3x]) = r3;
        }
        {
          int e = tid * 4, r = e >> 7, j = e & 127;
          int g = r >> 1, hh = r & 1;
          const float* wsrc; long rb;
          if (ch <= 8) { wsrc = wih0; rb = (long)(g * 512 + h0d + hh) * 1152 + ch * 128; }
          else         { wsrc = whh0; rb = (long)(g * 512 + h0d + hh) * 512 + (ch - 9) * 128; }
          *(float4*)(&wr[r * 132 + j]) = *(const float4*)(&wsrc[rb + j]);
        }
        __syncthreads();
        const int b = tid & 31, j0 = (tid >> 5) * 16;
#pragma unroll
        for (int jj = 0; jj < 16; jj += 4) {
          const float4 xv = *(const float4*)(&xs[b * 132 + j0 + jj]);
#pragma unroll
          for (int r = 0; r < 8; ++r) {
            const float4 w4 = *(const float4*)(&wr[r * 132 + j0 + jj]);
            acc[r] += xv.x * w4.x + xv.y * w4.y + xv.z * w4.z + xv.w * w4.w;
          }
        }
        __syncthreads();
      }
#pragma unroll
      for (int r = 0; r < 8; ++r) acc[r] += __shfl_down(acc[r], 32);
      if (ln < 32) {
#pragma unroll
        for (int r = 0; r < 8; ++r) gp[(wv * 32 + ln) * 8 + r] = acc[r];
      }
      __syncthreads();
      if (tid < 64) {
        const int b = tid & 31, hh = tid >> 5, h = h0d + hh;
        float gg[4];
#pragma unroll
        for (int g = 0; g < 4; ++g) {
          int r = g * 2 + hh;
          gg[g] = gp[(0 * 32 + b) * 8 + r] + gp[(1 * 32 + b) * 8 + r] +
                  gp[(2 * 32 + b) * 8 + r] + gp[(3 * 32 + b) * 8 + r] +
                  bih0[g * 512 + h] + bhh0[g * 512 + h];
        }
        float ig = sigm(gg[0]), fg = sigm(gg[1]), gt = tanh_f(gg[2]), og = sigm(gg[3]);
        int si = b * 512 + h;
        float c  = ld_dev1(st + C0O + p * 16384 + si);
        float cn = fg * c + ig * gt;
        float hn = og * tanh_f(cn);
        st_dev1(st + H0O + (p ^ 1) * 16384 + si, hn);
        st_dev1(st + C0O + (p ^ 1) * 16384 + si, cn);
      }
    }
    GBAR();

    // =================== Phase D: LSTM1 + q_next ===================
    {
      float* xs = smem;            // 32*132
      float* wr = smem + 4224;     // 12*132
      float* gp = smem + 5808;     // 4*32*12
      const int h0d = bid * 2;
      float acc[12];
#pragma unroll
      for (int r = 0; r < 12; ++r) acc[r] = 0.f;
      for (int ch = 0; ch < 8; ++ch) {
        const float* src = (ch < 4) ? (st + H0O + (p ^ 1) * 16384) : (st + H1O + p * 16384);
        const int col0 = (ch & 3) * 128;
        {
          int bs0 = (tid * 4) >> 7,          j0x = (tid * 4) & 127;
          int bs1 = (tid * 4 + 1024) >> 7,   j1x = (tid * 4 + 1024) & 127;
          int bs2 = (tid * 4 + 2048) >> 7,   j2x = (tid * 4 + 2048) & 127;
          int bs3 = (tid * 4 + 3072) >> 7,   j3x = (tid * 4 + 3072) & 127;
          float4 r0, r1, r2, r3;
          ld_dev4x4(src + bs0 * 512 + col0 + j0x, src + bs1 * 512 + col0 + j1x,
                    src + bs2 * 512 + col0 + j2x, src + bs3 * 512 + col0 + j3x,
                    r0, r1, r2, r3);
          *(float4*)(&xs[bs0 * 132 + j0x]) = r0;
          *(float4*)(&xs[bs1 * 132 + j1x]) = r1;
          *(float4*)(&xs[bs2 * 132 + j2x]) = r2;
          *(float4*)(&xs[bs3 * 132 + j3x]) = r3;
        }
        {
          int e = tid * 4, r = e >> 7, j = e & 127;
          int g = r >> 1, hh = r & 1;
          const float* wsrc = (ch < 4) ? wih1 : whh1;
          long rb = (long)(g * 512 + h0d + hh) * 512 + col0;
          *(float4*)(&wr[r * 132 + j]) = *(const float4*)(&wsrc[rb + j]);
          if (ch < 4 && tid < 128) {
            int rq = e >> 7, j2 = e & 127;
            long rqb = (long)(4 * bid + rq) * 512 + col0;
            *(float4*)(&wr[(8 + rq) * 132 + j2]) = *(const float4*)(&Wq[rqb + j2]);
          }
        }
        __syncthreads();
        const int b = tid & 31, j0 = (tid >> 5) * 16;
#pragma unroll
        for (int jj = 0; jj < 16; jj += 4) {
          const float4 xv = *(const float4*)(&xs[b * 132 + j0 + jj]);
#pragma unroll
          for (int r = 0; r < 8; ++r) {
            const float4 w4 = *(const float4*)(&wr[r * 132 + j0 + jj]);
            acc[r] += xv.x * w4.x + xv.y * w4.y + xv.z * w4.z + xv.w * w4.w;
          }
          if (ch < 4) {
#pragma unroll
            for (int r = 8; r < 12; ++r) {
              const float4 w4 = *(const float4*)(&wr[r * 132 + j0 + jj]);
              acc[r] += xv.x * w4.x + xv.y * w4.y + xv.z * w4.z + xv.w * w4.w;
            }
          }
        }
        __syncthreads();
      }
#pragma unroll
      for (int r = 0; r < 12; ++r) acc[r] += __shfl_down(acc[r], 32);
      if (ln < 32) {
#pragma unroll
        for (int r = 0; r < 12; ++r) gp[(wv * 32 + ln) * 12 + r] = acc[r];
      }
      __syncthreads();
      if (tid < 64) {
        const int b = tid & 31, hh = tid >> 5, h = h0d + hh;
        float gg[4];
#pragma unroll
        for (int g = 0; g < 4; ++g) {
          int r = g * 2 + hh;
          gg[g] = gp[(0 * 32 + b) * 12 + r] + gp[(1 * 32 + b) * 12 + r] +
                  gp[(2 * 32 + b) * 12 + r] + gp[(3 * 32 + b) * 12 + r] +
                  bih1[g * 512 + h] + bhh1[g * 512 + h];
        }
        float ig = sigm(gg[0]), fg = sigm(gg[1]), gt = tanh_f(gg[2]), og = sigm(gg[3]);
        int si = b * 512 + h;
        float c  = ld_dev1(st + C1O + p * 16384 + si);
        float cn = fg * c + ig * gt;
        float hn = og * tanh_f(cn);
        st_dev1(st + H1O + (p ^ 1) * 16384 + si, hn);
        st_dev1(st + C1O + (p ^ 1) * 16384 + si, cn);
        int r0 = 8 + 2 * hh;
        float q0 = gp[(0 * 32 + b) * 12 + r0]     + gp[(1 * 32 + b) * 12 + r0] +
                   gp[(2 * 32 + b) * 12 + r0]     + gp[(3 * 32 + b) * 12 + r0];
        float q1 = gp[(0 * 32 + b) * 12 + r0 + 1] + gp[(1 * 32 + b) * 12 + r0 + 1] +
                   gp[(2 * 32 + b) * 12 + r0 + 1] + gp[(3 * 32 + b) * 12 + r0 + 1];
        int o0 = 4 * bid + 2 * hh;
        st_dev1(st + QO + b * 1024 + o0,     q0);
        st_dev1(st + QO + b * 1024 + o0 + 1, q1);
      }
    }
    GBAR();
  }

  // =================== Tail: fc for step SD-1 (h1 at parity 0) ===================
  if (bid < 128) {
    float* h1s = smem;
    const int b = bid >> 2, og = (bid & 3) * 32;
    {
      const float* hp = st + H1O + b * 512;
      float r0, r1;
      ld_dev2(hp + tid, hp + tid + 256, r0, r1);
      h1s[tid] = r0; h1s[tid + 256] = r1;
    }
    __syncthreads();
#pragma unroll
    for (int oi = 0; oi < 8; ++oi) {
      const int o = og + wv * 8 + oi;
      float part = 0.f;
#pragma unroll
      for (int kk = 0; kk < 8; ++kk) {
        int k = kk * 64 + ln;
        part += h1s[k] * fcw[(long)o * 512 + k];
      }
      for (int off = 32; off; off >>= 1) part += __shfl_down(part, off);
      if (ln == 0) {
        float yh = fmaxf(part + fcb[o], 0.f);
        out[((long)b * SD + (SD - 1)) * 128 + o] = yh;
      }
    }
  }
#undef GBAR
}

extern "C" void kernel_launch(void* const* d_in, const int* in_sizes, int n_in,
                              void* d_out, int out_size, void* d_ws, size_t ws_size,
                              hipStream_t stream) {
  (void)in_sizes; (void)n_in; (void)out_size; (void)ws_size;
  float* out = (float*)d_out;

  const float* E    = (const float*)d_in[0];
  const float* h0   = (const float*)d_in[1];
  const float* c0   = (const float*)d_in[2];
  const float* Wk   = (const float*)d_in[3];
  const float* Wq   = (const float*)d_in[4];
  const float* Wv   = (const float*)d_in[5];
  const float* We   = (const float*)d_in[6];
  const float* wih0 = (const float*)d_in[7];
  const float* whh0 = (const float*)d_in[8];
  const float* bih0 = (const float*)d_in[9];
  const float* bhh0 = (const float*)d_in[10];
  const float* wih1 = (const float*)d_in[11];
  const float* whh1 = (const float*)d_in[12];
  const float* bih1 = (const float*)d_in[13];
  const float* bhh1 = (const float*)d_in[14];
  const float* fcw  = (const float*)d_in[15];
  const float* fcb  = (const float*)d_in[16];

  // ws layout: key bf16 33.5MB | value bf16 33.5MB | st ~1MB
  u16* key   = (u16*)d_ws;
  u16* value = key + 16777216;
  float* st  = (float*)d_ws + 16777216;   // byte 67,108,864

  gemm_kv<<<dim3(256, 16, 2), 256, 0, stream>>>(E, Wk, Wv, key, value);
  init_state<<<64, 256, 0, stream>>>(h0, c0, st);
  qproj<<<128, 256, 0, stream>>>(h0, Wq, st);

  decode_loop<<<256, 256, 0, stream>>>(key, value, We,
                                       wih0, whh0, bih0, bhh0,
                                       wih1, whh1, bih1, bhh1,
                                       Wq, fcw, fcb, st, out);
}